// Round 1
// baseline (230.228 us; speedup 1.0000x reference)
//
#include <hip/hip_runtime.h>
#include <stdint.h>

// LowRankConv2d: out[b,o,h,w] = (1/9)*sum_{k,r,c} Hm[k,o,r]*G[k,r,c]*x[b,c,h+i-1,w+j-1] + bias[o]
// Factored: stage1 T = G_all @ x (pointwise, M=288,K=256), stage2 = 9 shifted rank-32 MFMA GEMMs.
// bf16 MFMA both stages; fp32 accumulate; threshold 1.23e-2 >> expected ~1e-3 error.

#define BATCH 16
#define CIN   256
#define COUT  256
#define RANK  32
#define HH    56
#define WW    56
#define SP    (HH*WW)     // 3136
#define KR    (9*RANK)    // 288
#define YP    58          // padded rows (1..56 interior)
#define XP    58          // padded cols

typedef __bf16 bf16x8 __attribute__((ext_vector_type(8)));
typedef float  f32x4  __attribute__((ext_vector_type(4)));

// ws layout (bytes):
//  x_t   : [16][3136][256] bf16  = 25,690,112
//  T_pad : [16][58][58][288] bf16 = 31,002,624
//  G_bf  : [288][256] bf16        = 147,456
//  Hm_bf : [9][256][32] bf16      = 147,456
#define OFF_XT 0
#define OFF_TP 25690112
#define OFF_GB (OFF_TP + 31002624)
#define OFF_HB (OFF_GB + 147456)

__device__ __forceinline__ uint16_t f2bf_bits(float f) {
  union { float f; uint32_t u; } v; v.f = f;
  uint32_t u = v.u + 0x7fffu + ((v.u >> 16) & 1u);   // RNE
  return (uint16_t)(u >> 16);
}

__global__ __launch_bounds__(256) void k_cast(const float* __restrict__ src,
                                              uint16_t* __restrict__ dst, int n) {
  int i = blockIdx.x * 256 + threadIdx.x;
  if (i < n) dst[i] = f2bf_bits(src[i]);
}

// x (b,c,h,w) fp32 -> x_t[b][s][c] bf16, s = h*56+w.  LDS 64x64 tile transpose.
__global__ __launch_bounds__(256) void k_transpose(const float* __restrict__ x,
                                                   uint16_t* __restrict__ x_t) {
  __shared__ float tile[64][65];
  const int b = blockIdx.z, c0 = blockIdx.y * 64, s0 = blockIdx.x * 64;
  const int tid = threadIdx.x;
  const int a = tid & 63, g = tid >> 6;
#pragma unroll
  for (int r = 0; r < 16; ++r) {
    int c = g * 16 + r;
    tile[c][a] = x[((size_t)(b * CIN + c0 + c)) * SP + s0 + a];
  }
  __syncthreads();
#pragma unroll
  for (int r = 0; r < 16; ++r) {
    int s = g * 16 + r;
    x_t[((size_t)(b * SP + s0 + s)) * CIN + c0 + a] = f2bf_bits(tile[a][s]);
  }
}

// Stage 1: T_pad[b][h+1][w+1][kr] = sum_c G_all[kr][c] * x_t[b][s][c]
// Per wave: 16 spatial cols x full 288 kr rows, K=256 (8 MFMA k-steps).
// A = G_all (row-major, K-contig); B = x_t rows (K-contig). D rows = kr -> 8B bf16x4 store.
__global__ __launch_bounds__(256) void k_stage1(const uint16_t* __restrict__ x_t,
                                                const uint16_t* __restrict__ G_bf,
                                                uint16_t* __restrict__ T_pad) {
  const int b = blockIdx.y;
  const int wave = threadIdx.x >> 6;
  const int lane = threadIdx.x & 63;
  const int q = lane >> 4;
  const int t = lane & 15;
  const int s = blockIdx.x * 64 + wave * 16 + t;

  const uint16_t* xb = x_t + ((size_t)(b * SP + s)) * CIN + q * 8;
  bf16x8 bfrag[8];
#pragma unroll
  for (int ks = 0; ks < 8; ++ks)
    bfrag[ks] = *(const bf16x8*)(xb + ks * 32);

  const int h = s / WW, w = s - h * WW;
  uint16_t* stb = T_pad + (((size_t)b * YP + (h + 1)) * XP + (w + 1)) * KR + q * 4;
  const uint16_t* ga = G_bf + t * CIN + q * 8;

#pragma unroll
  for (int mt = 0; mt < 18; ++mt) {
    f32x4 acc = {0.f, 0.f, 0.f, 0.f};
#pragma unroll
    for (int ks = 0; ks < 8; ++ks) {
      bf16x8 afrag = *(const bf16x8*)(ga + (mt * 16) * CIN + ks * 32);
      acc = __builtin_amdgcn_mfma_f32_16x16x32_bf16(afrag, bfrag[ks], acc, 0, 0, 0);
    }
    // lane holds D[m=q*4+r][n=t]; kr = mt*16 + q*4 + r -> 4 consecutive bf16 (8B)
    uint32_t p0 = (uint32_t)f2bf_bits(acc[0]) | ((uint32_t)f2bf_bits(acc[1]) << 16);
    uint32_t p1 = (uint32_t)f2bf_bits(acc[2]) | ((uint32_t)f2bf_bits(acc[3]) << 16);
    uint2 pv; pv.x = p0; pv.y = p1;
    *(uint2*)(stb + mt * 16) = pv;
  }
}

// Stage 2: out[b,o,s] = (1/9)*sum_{tap} sum_r Hm[tap][o][r]*T_pad[b][h+i][w+j][tap*32+r] + bias[o]
// Per wave: M=16 spatial x N=256 o (16 n-tiles), K = 9 taps x 32.
// A = shifted T_pad rows (K-contig); B = Hm rows (K-contig). D rows = spatial -> float4 stores.
__global__ __launch_bounds__(256) void k_stage2(const uint16_t* __restrict__ T_pad,
                                                const uint16_t* __restrict__ Hm_bf,
                                                const float* __restrict__ bias,
                                                float* __restrict__ out) {
  const int b = blockIdx.y;
  const int wave = threadIdx.x >> 6;
  const int lane = threadIdx.x & 63;
  const int q = lane >> 4;
  const int t = lane & 15;
  const int sw = blockIdx.x * 64 + wave * 16;
  const int sa = sw + t;                 // this lane's A-row spatial index
  const int ha = sa / WW, wa = sa - ha * WW;

  const uint16_t* abase = T_pad + (((size_t)b * YP + ha) * XP + wa) * KR + q * 8;
  const uint16_t* bbase = Hm_bf + t * RANK + q * 8;

  f32x4 acc[16];
#pragma unroll
  for (int i = 0; i < 16; ++i) acc[i] = (f32x4){0.f, 0.f, 0.f, 0.f};

#pragma unroll
  for (int tap = 0; tap < 9; ++tap) {
    const int di = tap / 3, dj = tap % 3;
    bf16x8 afrag = *(const bf16x8*)(abase + (size_t)((di * XP + dj) * KR + tap * 32));
#pragma unroll
    for (int ot = 0; ot < 16; ++ot) {
      bf16x8 bfrag = *(const bf16x8*)(bbase + ((size_t)(tap * COUT + ot * 16)) * RANK);
      acc[ot] = __builtin_amdgcn_mfma_f32_16x16x32_bf16(afrag, bfrag, acc[ot], 0, 0, 0);
    }
  }

  const int sd = sw + q * 4;             // D rows: 4 consecutive spatial positions
#pragma unroll
  for (int ot = 0; ot < 16; ++ot) {
    const int o = ot * 16 + t;
    f32x4 v = acc[ot] * (1.0f / 9.0f) + bias[o];
    *(f32x4*)(out + ((size_t)(b * COUT + o)) * SP + sd) = v;
  }
}

extern "C" void kernel_launch(void* const* d_in, const int* in_sizes, int n_in,
                              void* d_out, int out_size, void* d_ws, size_t ws_size,
                              hipStream_t stream) {
  const float* x    = (const float*)d_in[0];
  const float* G    = (const float*)d_in[1];
  const float* Hm   = (const float*)d_in[2];
  const float* bias = (const float*)d_in[3];
  float* out = (float*)d_out;
  char* ws = (char*)d_ws;

  uint16_t* x_t   = (uint16_t*)(ws + OFF_XT);
  uint16_t* T_pad = (uint16_t*)(ws + OFF_TP);
  uint16_t* G_bf  = (uint16_t*)(ws + OFF_GB);
  uint16_t* Hm_bf = (uint16_t*)(ws + OFF_HB);

  // zero padded T ring (ws is poisoned 0xAA each call)
  hipMemsetAsync(T_pad, 0, 31002624, stream);

  k_cast<<<288, 256, 0, stream>>>(G, G_bf, 9 * RANK * CIN);
  k_cast<<<288, 256, 0, stream>>>(Hm, Hm_bf, 9 * COUT * RANK);
  k_transpose<<<dim3(SP / 64, CIN / 64, BATCH), 256, 0, stream>>>(x, x_t);
  k_stage1<<<dim3(SP / 64, BATCH), 256, 0, stream>>>(x_t, G_bf, T_pad);
  k_stage2<<<dim3(SP / 64, BATCH), 256, 0, stream>>>(T_pad, Hm_bf, bias, out);
}

// Round 2
// 207.876 us; speedup vs baseline: 1.1075x; 1.1075x over previous
//
#include <hip/hip_runtime.h>
#include <stdint.h>

// LowRankConv2d: out[b,o,h,w] = (1/9)*sum_{k,r,c} Hm[k,o,r]*G[k,r,c]*x[b,c,h+i-1,w+j-1] + bias[o]
// Stage1: T = G_all @ x (pointwise GEMM M=288,K=256,N=50176), T stored spatially padded.
// Stage2: 9 shifted rank-32 MFMA GEMM accumulations + /9 + bias epilogue.
// R2: weights register-resident, amortized over spatial loop (R1 refetched weights per-MFMA,
//     MfmaUtil 3.5%). Ring-zero instead of full memset; weight casts fused in-register.

#define BATCH 16
#define CIN   256
#define COUT  256
#define RANK  32
#define HH    56
#define WW    56
#define SP    (HH*WW)     // 3136
#define KR    (9*RANK)    // 288
#define YP    58
#define XP    58

typedef __bf16 bf16x8 __attribute__((ext_vector_type(8)));
typedef float  f32x4  __attribute__((ext_vector_type(4)));

// ws layout (bytes): x_t [16][3136][256] bf16 = 25,690,112 ; T_pad [16][58][58][288] bf16 = 31,002,624
#define OFF_XT 0
#define OFF_TP 25690112

__device__ __forceinline__ uint16_t f2bf_bits(float f) {
  union { float f; uint32_t u; } v; v.f = f;
  uint32_t u = v.u + 0x7fffu + ((v.u >> 16) & 1u);   // RNE
  return (uint16_t)(u >> 16);
}

__device__ __forceinline__ bf16x8 load_cvt8(const float* __restrict__ p) {
  bf16x8 f;
#pragma unroll
  for (int e = 0; e < 8; ++e) ((uint16_t*)&f)[e] = f2bf_bits(p[e]);
  return f;
}

// zero only the 1-cell border ring of T_pad (interior fully overwritten by stage1)
#define RING_U4 (16 * 228 * 36)   // 228 border cells/batch, 288 bf16 = 36 uint4 each
__global__ __launch_bounds__(256) void k_ring(uint16_t* __restrict__ T_pad) {
  int i = blockIdx.x * 256 + threadIdx.x;
  if (i >= RING_U4) return;
  int v = i % 36, cell = i / 36, b = cell / 228, c = cell % 228;
  int h, w;
  if      (c < 58)  { h = 0;       w = c;       }
  else if (c < 116) { h = 57;      w = c - 58;  }
  else if (c < 172) { h = c - 115; w = 0;       }
  else              { h = c - 171; w = 57;      }
  uint16_t* base = T_pad + (((size_t)b * YP + h) * XP + w) * KR;
  uint4 z; z.x = z.y = z.z = z.w = 0u;
  ((uint4*)base)[v] = z;
}

// x (b,c,h,w) fp32 -> x_t[b][s][c] bf16
__global__ __launch_bounds__(256) void k_transpose(const float* __restrict__ x,
                                                   uint16_t* __restrict__ x_t) {
  __shared__ float tile[64][65];
  const int b = blockIdx.z, c0 = blockIdx.y * 64, s0 = blockIdx.x * 64;
  const int a = threadIdx.x & 63, g = threadIdx.x >> 6;
#pragma unroll
  for (int r = 0; r < 16; ++r) {
    int c = g * 16 + r;
    tile[c][a] = x[((size_t)(b * CIN + c0 + c)) * SP + s0 + a];
  }
  __syncthreads();
#pragma unroll
  for (int r = 0; r < 16; ++r) {
    int s = g * 16 + r;
    x_t[((size_t)(b * SP + s0 + s)) * CIN + c0 + a] = f2bf_bits(tile[a][s]);
  }
}

// Stage 1. Grid (7 spatial-chunks, 6 m-groups, 16 batch), 4 waves/block.
// Wave holds A = 3 m-tiles of G (24 frags, cast once), loops 7 n-tiles of 16 spatial.
__global__ __launch_bounds__(256) void k_stage1(const float* __restrict__ G,
                                                const uint16_t* __restrict__ x_t,
                                                uint16_t* __restrict__ T_pad) {
  const int b = blockIdx.z, g = blockIdx.y;
  const int wave = threadIdx.x >> 6, lane = threadIdx.x & 63;
  const int q = lane >> 4, t = lane & 15;

  bf16x8 A[3][8];
  const float* gbase = G + ((size_t)(g * 48 + t)) * CIN + q * 8;
#pragma unroll
  for (int i = 0; i < 3; ++i)
#pragma unroll
    for (int ks = 0; ks < 8; ++ks)
      A[i][ks] = load_cvt8(gbase + (size_t)i * 16 * CIN + ks * 32);

  const int s0 = blockIdx.x * 448 + wave * 112 + t;   // per-lane spatial index

#pragma unroll 1
  for (int it = 0; it < 7; ++it) {
    const int s = s0 + it * 16;
    const uint16_t* xb = x_t + ((size_t)(b * SP + s)) * CIN + q * 8;
    bf16x8 Bf[8];
#pragma unroll
    for (int ks = 0; ks < 8; ++ks)
      Bf[ks] = *(const bf16x8*)(xb + ks * 32);

    f32x4 acc[3];
#pragma unroll
    for (int i = 0; i < 3; ++i) acc[i] = (f32x4){0.f, 0.f, 0.f, 0.f};
#pragma unroll
    for (int ks = 0; ks < 8; ++ks)
#pragma unroll
      for (int i = 0; i < 3; ++i)
        acc[i] = __builtin_amdgcn_mfma_f32_16x16x32_bf16(A[i][ks], Bf[ks], acc[i], 0, 0, 0);

    const int h = s / WW, w = s - h * WW;
    uint16_t* stb = T_pad + (((size_t)b * YP + (h + 1)) * XP + (w + 1)) * KR + g * 48 + q * 4;
#pragma unroll
    for (int i = 0; i < 3; ++i) {
      uint32_t p0 = (uint32_t)f2bf_bits(acc[i][0]) | ((uint32_t)f2bf_bits(acc[i][1]) << 16);
      uint32_t p1 = (uint32_t)f2bf_bits(acc[i][2]) | ((uint32_t)f2bf_bits(acc[i][3]) << 16);
      uint2 pv; pv.x = p0; pv.y = p1;
      *(uint2*)(stb + i * 16) = pv;
    }
  }
}

// Stage 2. Grid (7 spatial-chunks, 4 o-groups, 16 batch), 4 waves/block.
// Wave holds B = Hm frags for 4 o-tiles x 9 taps (36 frags, cast once), loops 7 n-tiles.
__global__ __launch_bounds__(256) void k_stage2(const uint16_t* __restrict__ T_pad,
                                                const float* __restrict__ Hm,
                                                const float* __restrict__ bias,
                                                float* __restrict__ out) {
  const int b = blockIdx.z, og = blockIdx.y;
  const int wave = threadIdx.x >> 6, lane = threadIdx.x & 63;
  const int q = lane >> 4, t = lane & 15;

  bf16x8 Bf[9][4];
  float bv[4];
#pragma unroll
  for (int j = 0; j < 4; ++j) {
    const int o = og * 64 + j * 16 + t;
    bv[j] = bias[o];
#pragma unroll
    for (int tap = 0; tap < 9; ++tap)
      Bf[tap][j] = load_cvt8(Hm + ((size_t)(tap * COUT + o)) * RANK + q * 8);
  }

  const int s0 = blockIdx.x * 448 + wave * 112;

#pragma unroll 1
  for (int it = 0; it < 7; ++it) {
    const int sw = s0 + it * 16;
    const int sa = sw + t;
    const int ha = sa / WW, wa = sa - ha * WW;
    const uint16_t* abase = T_pad + (((size_t)b * YP + ha) * XP + wa) * KR + q * 8;

    f32x4 acc[4];
#pragma unroll
    for (int j = 0; j < 4; ++j) acc[j] = (f32x4){0.f, 0.f, 0.f, 0.f};

#pragma unroll
    for (int tap = 0; tap < 9; ++tap) {
      const int di = tap / 3, dj = tap % 3;
      bf16x8 af = *(const bf16x8*)(abase + (size_t)((di * XP + dj) * KR + tap * 32));
#pragma unroll
      for (int j = 0; j < 4; ++j)
        acc[j] = __builtin_amdgcn_mfma_f32_16x16x32_bf16(af, Bf[tap][j], acc[j], 0, 0, 0);
    }

    const int sd = sw + q * 4;
#pragma unroll
    for (int j = 0; j < 4; ++j) {
      const int o = og * 64 + j * 16 + t;
      f32x4 v = acc[j] * (1.0f / 9.0f) + bv[j];
      *(f32x4*)(out + ((size_t)(b * COUT + o)) * SP + sd) = v;
    }
  }
}

extern "C" void kernel_launch(void* const* d_in, const int* in_sizes, int n_in,
                              void* d_out, int out_size, void* d_ws, size_t ws_size,
                              hipStream_t stream) {
  const float* x    = (const float*)d_in[0];
  const float* G    = (const float*)d_in[1];
  const float* Hm   = (const float*)d_in[2];
  const float* bias = (const float*)d_in[3];
  float* out = (float*)d_out;
  char* ws = (char*)d_ws;

  uint16_t* x_t   = (uint16_t*)(ws + OFF_XT);
  uint16_t* T_pad = (uint16_t*)(ws + OFF_TP);

  k_ring<<<(RING_U4 + 255) / 256, 256, 0, stream>>>(T_pad);
  k_transpose<<<dim3(SP / 64, CIN / 64, BATCH), 256, 0, stream>>>(x, x_t);
  k_stage1<<<dim3(7, 6, BATCH), 256, 0, stream>>>(G, x_t, T_pad);
  k_stage2<<<dim3(7, 4, BATCH), 256, 0, stream>>>(T_pad, Hm, bias, out);
}

// Round 3
// 180.539 us; speedup vs baseline: 1.2752x; 1.1514x over previous
//
#include <hip/hip_runtime.h>
#include <stdint.h>

// LowRankConv2d: out[b,o,h,w] = (1/9)*sum_{k,r,c} Hm[k,o,r]*G[k,r,c]*x[b,c,h+i-1,w+j-1] + bias[o]
// R3: per-tap T planes T9[tap][b][58][58][32] (coalesced stage2 reads), flattened (b,s) M-dim,
//     big grids (stage1 196x9, stage2 196x8) for occupancy. R2 was grid-starved (9% occ).

#define BATCH 16
#define CIN   256
#define COUT  256
#define RANK  32
#define HH    56
#define WW    56
#define SP    (HH*WW)        // 3136
#define NPOS  (BATCH*SP)     // 50176
#define YP    58
#define XP    58
#define PCELL (YP*XP)        // 3364 cells per (tap,b) plane
#define PLANE (BATCH*PCELL)  // cells per tap across batch

typedef __bf16 bf16x8 __attribute__((ext_vector_type(8)));
typedef float  f32x4  __attribute__((ext_vector_type(4)));

// ws layout (bytes):
//  x_t  [16][3136][256] bf16          = 25,690,112
//  T9   [9][16][58][58][32] bf16      = 31,002,624
//  G_bf [288][256] bf16               = 147,456
//  Hm_bf[9][256][32] bf16             = 147,456
#define OFF_XT 0
#define OFF_T9 25690112
#define OFF_GB (OFF_T9 + 31002624)
#define OFF_HB (OFF_GB + 147456)

__device__ __forceinline__ uint16_t bfbits(float f) {
  __bf16 h = (__bf16)f;
  return __builtin_bit_cast(uint16_t, h);
}

__device__ __forceinline__ bf16x8 load_cvt8(const float* __restrict__ p) {
  bf16x8 f;
#pragma unroll
  for (int e = 0; e < 8; ++e) ((__bf16*)&f)[e] = (__bf16)p[e];
  return f;
}

// cast G (73728) and Hm (73728) fp32 -> bf16 ws copies
__global__ __launch_bounds__(256) void k_wcast(const float* __restrict__ G,
                                               const float* __restrict__ Hm,
                                               uint16_t* __restrict__ G_bf,
                                               uint16_t* __restrict__ Hm_bf) {
  int i = blockIdx.x * 256 + threadIdx.x;
  if (i < 73728) G_bf[i] = bfbits(G[i]);
  else           Hm_bf[i - 73728] = bfbits(Hm[i - 73728]);
}

// zero the 1-cell border ring of each (tap,b) plane; interior fully written by stage1
#define RING_U4 (9 * 16 * 228 * 4)   // 228 border cells, 64B (=4 uint4) each
__global__ __launch_bounds__(256) void k_ring(uint16_t* __restrict__ T9) {
  int i = blockIdx.x * 256 + threadIdx.x;
  if (i >= RING_U4) return;
  int v = i & 3, cell = i >> 2;
  int tb = cell / 228, c = cell % 228;   // tb = tap*16 + b
  int y, x;
  if      (c < 58)  { y = 0;       x = c;       }
  else if (c < 116) { y = 57;      x = c - 58;  }
  else if (c < 172) { y = c - 115; x = 0;       }
  else              { y = c - 171; x = 57;      }
  uint16_t* base = T9 + ((size_t)tb * PCELL + y * XP + x) * 32;
  uint4 z; z.x = z.y = z.z = z.w = 0u;
  ((uint4*)base)[v] = z;
}

// x (b,c,h,w) fp32 -> x_t[b][s][c] bf16
__global__ __launch_bounds__(256) void k_transpose(const float* __restrict__ x,
                                                   uint16_t* __restrict__ x_t) {
  __shared__ float tile[64][65];
  const int b = blockIdx.z, c0 = blockIdx.y * 64, s0 = blockIdx.x * 64;
  const int a = threadIdx.x & 63, g = threadIdx.x >> 6;
#pragma unroll
  for (int r = 0; r < 16; ++r) {
    int c = g * 16 + r;
    tile[c][a] = x[((size_t)(b * CIN + c0 + c)) * SP + s0 + a];
  }
  __syncthreads();
#pragma unroll
  for (int r = 0; r < 16; ++r) {
    int s = g * 16 + r;
    x_t[((size_t)(b * SP + s0 + s)) * CIN + c0 + a] = bfbits(tile[a][s]);
  }
}

// Stage 1: T9[tap][cell][r] = sum_c G[tap*32+r][c] * x_t[p][c]
// grid (196, 9): blockIdx.y = tap. Wave: A = tap's 32 rows (16 frags, reg-resident),
// 4 n-tiles of 16 positions. Per tile: 8 B-loads, 16 MFMAs, 2 stores.
__global__ __launch_bounds__(256) void k_stage1(const uint16_t* __restrict__ G_bf,
                                                const uint16_t* __restrict__ x_t,
                                                uint16_t* __restrict__ T9) {
  const int tap = blockIdx.y;
  const int wave = threadIdx.x >> 6, lane = threadIdx.x & 63;
  const int q = lane >> 4, t = lane & 15;

  bf16x8 A[2][8];
  {
    const uint16_t* gb = G_bf + ((size_t)(tap * 32 + t)) * CIN + q * 8;
#pragma unroll
    for (int mt = 0; mt < 2; ++mt)
#pragma unroll
      for (int ks = 0; ks < 8; ++ks)
        A[mt][ks] = *(const bf16x8*)(gb + (size_t)mt * 16 * CIN + ks * 32);
  }

  uint16_t* plane = T9 + (size_t)tap * PLANE * 32;
  const int tile0 = blockIdx.x * 16 + wave * 4;

#pragma unroll 1
  for (int it = 0; it < 4; ++it) {
    const int p = (tile0 + it) * 16 + t;          // this lane's position (B col / store row)
    const uint16_t* xb = x_t + (size_t)p * CIN + q * 8;
    bf16x8 Bf[8];
#pragma unroll
    for (int ks = 0; ks < 8; ++ks)
      Bf[ks] = *(const bf16x8*)(xb + ks * 32);

    f32x4 acc[2];
    acc[0] = (f32x4){0.f, 0.f, 0.f, 0.f};
    acc[1] = (f32x4){0.f, 0.f, 0.f, 0.f};
#pragma unroll
    for (int ks = 0; ks < 8; ++ks) {
      acc[0] = __builtin_amdgcn_mfma_f32_16x16x32_bf16(A[0][ks], Bf[ks], acc[0], 0, 0, 0);
      acc[1] = __builtin_amdgcn_mfma_f32_16x16x32_bf16(A[1][ks], Bf[ks], acc[1], 0, 0, 0);
    }

    // D[m = q*4+r][n = t] ; store lane's (cell = pos t) channels mt*16+q*4 .. +3
    const int b = p / SP, s = p - b * SP;
    const int h = s / WW, w = s - h * WW;
    uint16_t* stb = plane + ((size_t)(b * PCELL + (h + 1) * XP + (w + 1))) * 32 + q * 4;
#pragma unroll
    for (int mt = 0; mt < 2; ++mt) {
      uint2 pv;
      pv.x = (uint32_t)bfbits(acc[mt][0]) | ((uint32_t)bfbits(acc[mt][1]) << 16);
      pv.y = (uint32_t)bfbits(acc[mt][2]) | ((uint32_t)bfbits(acc[mt][3]) << 16);
      *(uint2*)(stb + mt * 16) = pv;
    }
  }
}

// Stage 2: out[p][o] = (1/9)*sum_tap sum_r T9[tap][cell(p)+shift][r]*Hm[tap][o][r] + bias[o]
// grid (196, 8): blockIdx.y = o-group of 32. Wave: B = 18 reg-resident Hm frags,
// 4 m-tiles of 16 positions. Per tile: 9 A-loads (1KB coalesced), 18 MFMAs, 2 f32x4 stores.
__global__ __launch_bounds__(256) void k_stage2(const uint16_t* __restrict__ T9,
                                                const uint16_t* __restrict__ Hm_bf,
                                                const float* __restrict__ bias,
                                                float* __restrict__ out) {
  const int og = blockIdx.y;
  const int wave = threadIdx.x >> 6, lane = threadIdx.x & 63;
  const int q = lane >> 4, t = lane & 15;

  bf16x8 Bf[9][2];
  float bv[2];
#pragma unroll
  for (int j = 0; j < 2; ++j) {
    const int o = og * 32 + j * 16 + t;
    bv[j] = bias[o];
#pragma unroll
    for (int tap = 0; tap < 9; ++tap)
      Bf[tap][j] = *(const bf16x8*)(Hm_bf + ((size_t)(tap * COUT + o)) * RANK + q * 8);
  }

  const int tile0 = blockIdx.x * 16 + wave * 4;

#pragma unroll 1
  for (int it = 0; it < 4; ++it) {
    const int p0 = (tile0 + it) * 16;
    const int pa = p0 + t;                        // this lane's A row (position)
    const int b = pa / SP, s = pa - b * SP;
    const int ha = s / WW, wa = s - ha * WW;
    const uint16_t* abase = T9 + ((size_t)(b * PCELL + ha * XP + wa)) * 32 + q * 8;

    f32x4 acc[2];
    acc[0] = (f32x4){0.f, 0.f, 0.f, 0.f};
    acc[1] = (f32x4){0.f, 0.f, 0.f, 0.f};
#pragma unroll
    for (int tap = 0; tap < 9; ++tap) {
      const int di = tap / 3, dj = tap % 3;
      bf16x8 af = *(const bf16x8*)(abase + (size_t)tap * PLANE * 32 + (di * XP + dj) * 32);
      acc[0] = __builtin_amdgcn_mfma_f32_16x16x32_bf16(af, Bf[tap][0], acc[0], 0, 0, 0);
      acc[1] = __builtin_amdgcn_mfma_f32_16x16x32_bf16(af, Bf[tap][1], acc[1], 0, 0, 0);
    }

    // D rows = positions p0 + q*4 .. +3 (same batch: tiles never cross batch, SP%16==0)
    const int bd = p0 / SP, sd = p0 - bd * SP + q * 4;
#pragma unroll
    for (int j = 0; j < 2; ++j) {
      const int o = og * 32 + j * 16 + t;
      f32x4 v = acc[j] * (1.0f / 9.0f) + bv[j];
      *(f32x4*)(out + ((size_t)(bd * COUT + o)) * SP + sd) = v;
    }
  }
}

extern "C" void kernel_launch(void* const* d_in, const int* in_sizes, int n_in,
                              void* d_out, int out_size, void* d_ws, size_t ws_size,
                              hipStream_t stream) {
  const float* x    = (const float*)d_in[0];
  const float* G    = (const float*)d_in[1];
  const float* Hm   = (const float*)d_in[2];
  const float* bias = (const float*)d_in[3];
  float* out = (float*)d_out;
  char* ws = (char*)d_ws;

  uint16_t* x_t   = (uint16_t*)(ws + OFF_XT);
  uint16_t* T9    = (uint16_t*)(ws + OFF_T9);
  uint16_t* G_bf  = (uint16_t*)(ws + OFF_GB);
  uint16_t* Hm_bf = (uint16_t*)(ws + OFF_HB);

  k_wcast<<<(147456 + 255) / 256, 256, 0, stream>>>(G, Hm, G_bf, Hm_bf);
  k_ring<<<(RING_U4 + 255) / 256, 256, 0, stream>>>(T9);
  k_transpose<<<dim3(SP / 64, CIN / 64, BATCH), 256, 0, stream>>>(x, x_t);
  k_stage1<<<dim3(196, 9), 256, 0, stream>>>(G_bf, x_t, T9);
  k_stage2<<<dim3(196, 8), 256, 0, stream>>>(T9, Hm_bf, bias, out);
}

// Round 4
// 156.600 us; speedup vs baseline: 1.4702x; 1.1529x over previous
//
#include <hip/hip_runtime.h>
#include <stdint.h>

// LowRankConv2d: out[b,o,h,w] = (1/9)*sum_{k,r,c} Hm[k,o,r]*G[k,r,c]*x[b,c,h+i-1,w+j-1] + bias[o]
// R4: block-internal coverage of the reduction-orthogonal dim so big operands are read from
//     HBM exactly once (R3 re-read x_t 9x / T9 8x across blocks: stage1 FETCH 82MB vs 26MB ideal).
//     stage1: 6-wave block holds all 288 G-rows in regs, waves share x_t loads via L1.
//     stage2: 4-wave block holds all 256 o-cols of Hm in regs, waves share T9 loads via L1.
//     Persistent grids (512 blocks = 2/CU) to amortize weight setup.

#define BATCH 16
#define CIN   256
#define COUT  256
#define RANK  32
#define HH    56
#define WW    56
#define SP    (HH*WW)        // 3136
#define NPOS  (BATCH*SP)     // 50176
#define YP    58
#define XP    58
#define PCELL (YP*XP)        // 3364 cells per (tap,b) plane
#define PLANE (BATCH*PCELL)

typedef __bf16 bf16x8 __attribute__((ext_vector_type(8)));
typedef float  f32x4  __attribute__((ext_vector_type(4)));

// ws layout (bytes):
//  x_t  [16][3136][256] bf16      = 25,690,112
//  T9   [9][16][58][58][32] bf16  = 31,002,624
//  G_bf [288][256] bf16           = 147,456
//  Hm_bf[9][256][32] bf16         = 147,456
#define OFF_XT 0
#define OFF_T9 25690112
#define OFF_GB (OFF_T9 + 31002624)
#define OFF_HB (OFF_GB + 147456)

__device__ __forceinline__ uint16_t bfbits(float f) {
  __bf16 h = (__bf16)f;
  return __builtin_bit_cast(uint16_t, h);
}

__global__ __launch_bounds__(256) void k_wcast(const float* __restrict__ G,
                                               const float* __restrict__ Hm,
                                               uint16_t* __restrict__ G_bf,
                                               uint16_t* __restrict__ Hm_bf) {
  int i = blockIdx.x * 256 + threadIdx.x;
  if (i < 73728) G_bf[i] = bfbits(G[i]);
  else           Hm_bf[i - 73728] = bfbits(Hm[i - 73728]);
}

// zero the 1-cell border ring of each (tap,b) plane; interior fully written by stage1
#define RING_U4 (9 * 16 * 228 * 4)
__global__ __launch_bounds__(256) void k_ring(uint16_t* __restrict__ T9) {
  int i = blockIdx.x * 256 + threadIdx.x;
  if (i >= RING_U4) return;
  int v = i & 3, cell = i >> 2;
  int tb = cell / 228, c = cell % 228;
  int y, x;
  if      (c < 58)  { y = 0;       x = c;       }
  else if (c < 116) { y = 57;      x = c - 58;  }
  else if (c < 172) { y = c - 115; x = 0;       }
  else              { y = c - 171; x = 57;      }
  uint16_t* base = T9 + ((size_t)tb * PCELL + y * XP + x) * 32;
  uint4 z; z.x = z.y = z.z = z.w = 0u;
  ((uint4*)base)[v] = z;
}

// x (b,c,h,w) fp32 -> x_t[b][s][c] bf16
__global__ __launch_bounds__(256) void k_transpose(const float* __restrict__ x,
                                                   uint16_t* __restrict__ x_t) {
  __shared__ float tile[64][65];
  const int b = blockIdx.z, c0 = blockIdx.y * 64, s0 = blockIdx.x * 64;
  const int a = threadIdx.x & 63, g = threadIdx.x >> 6;
#pragma unroll
  for (int r = 0; r < 16; ++r) {
    int c = g * 16 + r;
    tile[c][a] = x[((size_t)(b * CIN + c0 + c)) * SP + s0 + a];
  }
  __syncthreads();
#pragma unroll
  for (int r = 0; r < 16; ++r) {
    int s = g * 16 + r;
    x_t[((size_t)(b * SP + s0 + s)) * CIN + c0 + a] = bfbits(tile[a][s]);
  }
}

// Stage 1: T9[tap][cell][r] = sum_c G[tap*32+r][c] * x_t[p][c]
// 6 waves: wave w owns M-rows 48w..48w+47 (3 m-tiles, reg-resident A).
// All waves sweep identical x_t n-tiles -> L1-shared B loads.
// Persistent grid 512; items = (b, 32-pos chunk) = 16*98 = 1568.
__global__ __launch_bounds__(384, 3) void k_stage1(const uint16_t* __restrict__ G_bf,
                                                   const uint16_t* __restrict__ x_t,
                                                   uint16_t* __restrict__ T9) {
  const int wave = threadIdx.x >> 6, lane = threadIdx.x & 63;
  const int q = lane >> 4, t = lane & 15;

  bf16x8 A[3][8];
  {
    const uint16_t* gb = G_bf + ((size_t)(wave * 48 + t)) * CIN + q * 8;
#pragma unroll
    for (int i = 0; i < 3; ++i)
#pragma unroll
      for (int ks = 0; ks < 8; ++ks)
        A[i][ks] = *(const bf16x8*)(gb + (size_t)i * 16 * CIN + ks * 32);
  }

#pragma unroll 1
  for (int item = blockIdx.x; item < 1568; item += 512) {
    const int b = item & 15, ch = item >> 4;
#pragma unroll 1
    for (int it = 0; it < 2; ++it) {
      const int p = ch * 32 + it * 16 + t;        // lane's position (B col / store cell)
      const uint16_t* xb = x_t + ((size_t)b * SP + p) * CIN + q * 8;
      bf16x8 Bf[8];
#pragma unroll
      for (int ks = 0; ks < 8; ++ks)
        Bf[ks] = *(const bf16x8*)(xb + ks * 32);

      f32x4 acc[3];
#pragma unroll
      for (int i = 0; i < 3; ++i) acc[i] = (f32x4){0.f, 0.f, 0.f, 0.f};
#pragma unroll
      for (int ks = 0; ks < 8; ++ks)
#pragma unroll
        for (int i = 0; i < 3; ++i)
          acc[i] = __builtin_amdgcn_mfma_f32_16x16x32_bf16(A[i][ks], Bf[ks], acc[i], 0, 0, 0);

      const int h = p / WW, w = p - (p / WW) * WW;
      const size_t cellbase = ((size_t)b * PCELL + (h + 1) * XP + (w + 1)) * 32;
#pragma unroll
      for (int i = 0; i < 3; ++i) {
        const int kr0 = wave * 48 + i * 16 + q * 4;   // 4-run stays within one tap (4|32)
        const int tap = kr0 >> 5, r = kr0 & 31;
        uint2 pv;
        pv.x = (uint32_t)bfbits(acc[i][0]) | ((uint32_t)bfbits(acc[i][1]) << 16);
        pv.y = (uint32_t)bfbits(acc[i][2]) | ((uint32_t)bfbits(acc[i][3]) << 16);
        *(uint2*)(T9 + (size_t)tap * PLANE * 32 + cellbase + r) = pv;
      }
    }
  }
}

// Stage 2: out[p][o] = (1/9)*sum_tap sum_r T9[tap][cell(p)+shift][r]*Hm[tap][o][r] + bias[o]
// 4 waves: wave w owns o in [64w,64w+64) (Bf[9][4] reg-resident).
// All waves read identical T9 A-tiles -> L1-shared. Persistent grid 512 over 3136 m-tiles.
__global__ __launch_bounds__(256, 2) void k_stage2(const uint16_t* __restrict__ T9,
                                                   const uint16_t* __restrict__ Hm_bf,
                                                   const float* __restrict__ bias,
                                                   float* __restrict__ out) {
  const int wave = threadIdx.x >> 6, lane = threadIdx.x & 63;
  const int q = lane >> 4, t = lane & 15;

  bf16x8 Bf[9][4];
  float bv[4];
#pragma unroll
  for (int j = 0; j < 4; ++j) {
    const int o = wave * 64 + j * 16 + t;
    bv[j] = bias[o];
#pragma unroll
    for (int tap = 0; tap < 9; ++tap)
      Bf[tap][j] = *(const bf16x8*)(Hm_bf + ((size_t)(tap * COUT + o)) * RANK + q * 8);
  }

#pragma unroll 1
  for (int mt = blockIdx.x; mt < 3136; mt += 512) {
    const int p0 = mt * 16;
    const int b = p0 / SP, s0 = p0 - b * SP;
    const int sa = s0 + t;
    const int ha = sa / WW, wa = sa - ha * WW;
    const uint16_t* abase = T9 + ((size_t)(b * PCELL + ha * XP + wa)) * 32 + q * 8;

    f32x4 acc[4];
#pragma unroll
    for (int j = 0; j < 4; ++j) acc[j] = (f32x4){0.f, 0.f, 0.f, 0.f};

#pragma unroll
    for (int tap = 0; tap < 9; ++tap) {
      const int di = tap / 3, dj = tap % 3;
      bf16x8 af = *(const bf16x8*)(abase + (size_t)tap * PLANE * 32 + (di * XP + dj) * 32);
#pragma unroll
      for (int j = 0; j < 4; ++j)
        acc[j] = __builtin_amdgcn_mfma_f32_16x16x32_bf16(af, Bf[tap][j], acc[j], 0, 0, 0);
    }

    const int sd = s0 + q * 4;                    // D rows = 4 consecutive positions
#pragma unroll
    for (int j = 0; j < 4; ++j) {
      const int o = wave * 64 + j * 16 + t;
      f32x4 v = acc[j] * (1.0f / 9.0f) + bv[j];
      *(f32x4*)(out + ((size_t)(b * COUT + o)) * SP + sd) = v;
    }
  }
}

extern "C" void kernel_launch(void* const* d_in, const int* in_sizes, int n_in,
                              void* d_out, int out_size, void* d_ws, size_t ws_size,
                              hipStream_t stream) {
  const float* x    = (const float*)d_in[0];
  const float* G    = (const float*)d_in[1];
  const float* Hm   = (const float*)d_in[2];
  const float* bias = (const float*)d_in[3];
  float* out = (float*)d_out;
  char* ws = (char*)d_ws;

  uint16_t* x_t   = (uint16_t*)(ws + OFF_XT);
  uint16_t* T9    = (uint16_t*)(ws + OFF_T9);
  uint16_t* G_bf  = (uint16_t*)(ws + OFF_GB);
  uint16_t* Hm_bf = (uint16_t*)(ws + OFF_HB);

  k_wcast<<<576, 256, 0, stream>>>(G, Hm, G_bf, Hm_bf);
  k_ring<<<(RING_U4 + 255) / 256, 256, 0, stream>>>(T9);
  k_transpose<<<dim3(49, 4, 16), 256, 0, stream>>>(x, x_t);
  k_stage1<<<512, 384, 0, stream>>>(G_bf, x_t, T9);
  k_stage2<<<512, 256, 0, stream>>>(T9, Hm_bf, bias, out);
}

// Round 5
// 142.552 us; speedup vs baseline: 1.6150x; 1.0985x over previous
//
#include <hip/hip_runtime.h>
#include <stdint.h>

// LowRankConv2d: out[b,o,h,w] = (1/9)*sum_{k,r,c} Hm[k,o,r]*G[k,r,c]*x[b,c,h+i-1,w+j-1] + bias[o]
// R5: fuse transpose+cast+stage1 (x fp32 NCHW -> LDS bf16 channel-minor tile -> MFMA -> T9),
//     eliminating the x_t HBM round-trip (52 MB) and 2 of 5 launches. Stage2 re-blocked to
//     512 thr / wave-owns-32-o (Bf[9][2]=72 VGPR) for 16 waves/CU (R4 had only 8).

#define BATCH 16
#define CIN   256
#define COUT  256
#define RANK  32
#define HH    56
#define WW    56
#define SP    (HH*WW)        // 3136
#define YP    58
#define XP    58
#define PCELL (YP*XP)        // 3364
#define PLANE (BATCH*PCELL)

typedef __bf16 bf16x8 __attribute__((ext_vector_type(8)));
typedef float  f32x4  __attribute__((ext_vector_type(4)));

// ws layout (bytes):
//  T9   [9][16][58][58][32] bf16  = 31,002,624
//  G_bf [288][256] bf16           = 147,456
//  Hm_bf[9][256][32] bf16         = 147,456
#define OFF_T9 0
#define OFF_GB 31002624
#define OFF_HB (OFF_GB + 147456)

#define RING_U4 (9 * 16 * 228 * 4)   // border cells * 64B(=4 uint4)
#define PREP_N  (147456 + RING_U4)   // 278,784

__device__ __forceinline__ uint16_t bfbits(float f) {
  __bf16 h = (__bf16)f;
  return __builtin_bit_cast(uint16_t, h);
}

// weight casts + T9 border ring zero, one launch
__global__ __launch_bounds__(256) void k_prep(const float* __restrict__ G,
                                              const float* __restrict__ Hm,
                                              uint16_t* __restrict__ G_bf,
                                              uint16_t* __restrict__ Hm_bf,
                                              uint16_t* __restrict__ T9) {
  int i = blockIdx.x * 256 + threadIdx.x;
  if (i < 73728)  { G_bf[i] = bfbits(G[i]); return; }
  if (i < 147456) { Hm_bf[i - 73728] = bfbits(Hm[i - 73728]); return; }
  int j = i - 147456;
  if (j >= RING_U4) return;
  int v = j & 3, cell = j >> 2;
  int tb = cell / 228, c = cell % 228;
  int y, xx;
  if      (c < 58)  { y = 0;       xx = c;       }
  else if (c < 116) { y = 57;      xx = c - 58;  }
  else if (c < 172) { y = c - 115; xx = 0;       }
  else              { y = c - 171; xx = 57;      }
  uint16_t* base = T9 + ((size_t)tb * PCELL + y * XP + xx) * 32;
  uint4 z; z.x = z.y = z.z = z.w = 0u;
  ((uint4*)base)[v] = z;
}

// Fused transpose+cast+stage1: T9[tap][cell][r] = sum_c G[tap*32+r][c] * x[b][c][s]
// Block: 384 thr (6 waves); wave w holds G rows 48w..48w+47 reg-resident (24 frags).
// Per item (b, 32-pos chunk): stage x into LDS bf16 [32 s][264 c-padded] (transpose via LDS),
// then 2 n-tiles of 16 pos: 8x ds_read_b128 B-frags, 24 MFMA, 3 uint2 stores per wave.
__global__ __launch_bounds__(384, 3) void k_fused1(const float* __restrict__ x,
                                                   const uint16_t* __restrict__ G_bf,
                                                   uint16_t* __restrict__ T9) {
  __shared__ uint16_t xs[32 * 264];
  const int tid = threadIdx.x;
  const int wave = tid >> 6, lane = tid & 63;
  const int q = lane >> 4, t = lane & 15;

  bf16x8 A[3][8];
  {
    const uint16_t* gb = G_bf + (size_t)(wave * 48 + t) * CIN + q * 8;
#pragma unroll
    for (int i = 0; i < 3; ++i)
#pragma unroll
      for (int ks = 0; ks < 8; ++ks)
        A[i][ks] = *(const bf16x8*)(gb + (size_t)i * 16 * CIN + ks * 32);
  }

#pragma unroll 1
  for (int item = blockIdx.x; item < 1568; item += 512) {
    const int b = item / 98, ch = item - b * 98;    // 98 chunks of 32 positions per batch

    // stage: 1024 units = (s 0..31, cg 0..31); unit loads 8 c-rows (s-coalesced), writes 16B
#pragma unroll 1
    for (int u = tid; u < 1024; u += 384) {
      const int s = u & 31, cg = u >> 5;
      const float* xr = x + ((size_t)(b * CIN + cg * 8)) * SP + ch * 32 + s;
      bf16x8 v;
#pragma unroll
      for (int e = 0; e < 8; ++e)
        ((__bf16*)&v)[e] = (__bf16)xr[(size_t)e * SP];
      *(bf16x8*)&xs[s * 264 + cg * 8] = v;
    }
    __syncthreads();

#pragma unroll 1
    for (int nt = 0; nt < 2; ++nt) {
      bf16x8 Bf[8];
#pragma unroll
      for (int ks = 0; ks < 8; ++ks)
        Bf[ks] = *(const bf16x8*)&xs[(nt * 16 + t) * 264 + ks * 32 + q * 8];

      f32x4 acc[3];
#pragma unroll
      for (int i = 0; i < 3; ++i) acc[i] = (f32x4){0.f, 0.f, 0.f, 0.f};
#pragma unroll
      for (int ks = 0; ks < 8; ++ks)
#pragma unroll
        for (int i = 0; i < 3; ++i)
          acc[i] = __builtin_amdgcn_mfma_f32_16x16x32_bf16(A[i][ks], Bf[ks], acc[i], 0, 0, 0);

      const int p = ch * 32 + nt * 16 + t;          // lane's store cell (D col = t)
      const int h = p / WW, w = p - (p / WW) * WW;
      const size_t cellbase = ((size_t)b * PCELL + (h + 1) * XP + (w + 1)) * 32;
#pragma unroll
      for (int i = 0; i < 3; ++i) {
        const int kr0 = wave * 48 + i * 16 + q * 4; // 4-run stays within one tap (4|32)
        const int tap = kr0 >> 5, r = kr0 & 31;
        uint2 pv;
        pv.x = (uint32_t)bfbits(acc[i][0]) | ((uint32_t)bfbits(acc[i][1]) << 16);
        pv.y = (uint32_t)bfbits(acc[i][2]) | ((uint32_t)bfbits(acc[i][3]) << 16);
        *(uint2*)(T9 + (size_t)tap * PLANE * 32 + cellbase + r) = pv;
      }
    }
    __syncthreads();
  }
}

// Stage 2: out[p][o] = (1/9)*sum_tap sum_r T9[tap][cell(p)+shift][r]*Hm[tap][o][r] + bias[o]
// Block: 512 thr (8 waves); wave w owns o in [32w, 32w+32): Bf[9][2] reg-resident (72 VGPR)
// -> 16 waves/CU. All 8 waves read identical T9 A-tiles (L1-shared). Persistent grid 512.
__global__ __launch_bounds__(512, 4) void k_stage2(const uint16_t* __restrict__ T9,
                                                   const uint16_t* __restrict__ Hm_bf,
                                                   const float* __restrict__ bias,
                                                   float* __restrict__ out) {
  const int wave = threadIdx.x >> 6, lane = threadIdx.x & 63;
  const int q = lane >> 4, t = lane & 15;

  bf16x8 Bf[9][2];
  float bv[2];
#pragma unroll
  for (int j = 0; j < 2; ++j) {
    const int o = wave * 32 + j * 16 + t;
    bv[j] = bias[o];
#pragma unroll
    for (int tap = 0; tap < 9; ++tap)
      Bf[tap][j] = *(const bf16x8*)(Hm_bf + ((size_t)(tap * COUT + o)) * RANK + q * 8);
  }

#pragma unroll 1
  for (int mt = blockIdx.x; mt < 3136; mt += 512) {
    const int p0 = mt * 16;
    const int b = p0 / SP, s0 = p0 - b * SP;
    const int sa = s0 + t;
    const int ha = sa / WW, wa = sa - ha * WW;
    const uint16_t* abase = T9 + ((size_t)(b * PCELL + ha * XP + wa)) * 32 + q * 8;

    f32x4 acc[2];
    acc[0] = (f32x4){0.f, 0.f, 0.f, 0.f};
    acc[1] = (f32x4){0.f, 0.f, 0.f, 0.f};
#pragma unroll
    for (int tap = 0; tap < 9; ++tap) {
      const int di = tap / 3, dj = tap % 3;
      bf16x8 af = *(const bf16x8*)(abase + (size_t)tap * PLANE * 32 + (di * XP + dj) * 32);
      acc[0] = __builtin_amdgcn_mfma_f32_16x16x32_bf16(af, Bf[0 + tap][0], acc[0], 0, 0, 0);
      acc[1] = __builtin_amdgcn_mfma_f32_16x16x32_bf16(af, Bf[0 + tap][1], acc[1], 0, 0, 0);
    }

    const int sd = s0 + q * 4;                      // D rows = 4 consecutive positions
#pragma unroll
    for (int j = 0; j < 2; ++j) {
      const int o = wave * 32 + j * 16 + t;
      f32x4 v = acc[j] * (1.0f / 9.0f) + bv[j];
      *(f32x4*)(out + ((size_t)(b * COUT + o)) * SP + sd) = v;
    }
  }
}

extern "C" void kernel_launch(void* const* d_in, const int* in_sizes, int n_in,
                              void* d_out, int out_size, void* d_ws, size_t ws_size,
                              hipStream_t stream) {
  const float* x    = (const float*)d_in[0];
  const float* G    = (const float*)d_in[1];
  const float* Hm   = (const float*)d_in[2];
  const float* bias = (const float*)d_in[3];
  float* out = (float*)d_out;
  char* ws = (char*)d_ws;

  uint16_t* T9    = (uint16_t*)(ws + OFF_T9);
  uint16_t* G_bf  = (uint16_t*)(ws + OFF_GB);
  uint16_t* Hm_bf = (uint16_t*)(ws + OFF_HB);

  k_prep<<<PREP_N / 256, 256, 0, stream>>>(G, Hm, G_bf, Hm_bf, T9);
  k_fused1<<<512, 384, 0, stream>>>(x, G_bf, T9);
  k_stage2<<<512, 512, 0, stream>>>(T9, Hm_bf, bias, out);
}